// Round 9
// baseline (2525.862 us; speedup 1.0000x reference)
//
#include <hip/hip_runtime.h>

#define T_STEPS 19
#define NBATCH  65536
#define RNN     256
#define EMB     128
#define KDIM    384   // RNN + EMB
#define ROWB    768   // KDIM * 2 bytes (LDS row stride)
#define ABUF    49152 // bytes per A buffer = 64 * ROWB  (was 98304: buffer overlay bug)
#define SWZ(row) (((row) & 15) << 4)

typedef __bf16 bf16x8 __attribute__((ext_vector_type(8)));
typedef float  f32x4  __attribute__((ext_vector_type(4)));

#define BLOCK_SYNC() asm volatile("s_waitcnt lgkmcnt(0)\n\ts_barrier" ::: "memory")

__device__ __forceinline__ unsigned short f2bf(float f) {
    unsigned u = __float_as_uint(f);
    u += 0x7fffu + ((u >> 16) & 1u);
    return (unsigned short)(u >> 16);
}
__device__ __forceinline__ float bf2f(unsigned short u) {
    return __uint_as_float(((unsigned)u) << 16);
}
__device__ __forceinline__ float sigm_(float x) {
    float e = __expf(-x);
    return __builtin_amdgcn_rcpf(1.0f + e);
}
__device__ __forceinline__ float tanh_(float x) {
    float e = __expf(2.0f * x);
    return 1.0f - 2.0f * __builtin_amdgcn_rcpf(e + 1.0f);
}

// ---- prep: Wcat fragments for 16x16x32 MFMA, wave-private slices ----
// uint4 idx = ((w*12 + kk)*4 + g)*64 + l
//   j = g*256 + w*16 + (l&15) ; k = kk*32 + (l>>4)*8 + e
__global__ void prep_wcat(const float* __restrict__ Whh, const float* __restrict__ Wih,
                          unsigned short* __restrict__ dst) {
    int tid = blockIdx.x * 256 + threadIdx.x;   // 49152 total
    int l   = tid & 63;
    int p   = tid >> 6;
    int g   = p & 3;
    int kkw = p >> 2;
    int kk  = kkw % 12;
    int w   = kkw / 12;
    int j   = g * 256 + w * 16 + (l & 15);
    int kb  = kk * 32 + (l >> 4) * 8;
    unsigned short v[8];
#pragma unroll
    for (int e = 0; e < 8; ++e) {
        int k = kb + e;
        float f = (k < 256) ? Whh[j * 256 + k] : Wih[j * 128 + (k - 256)];
        v[e] = f2bf(f);
    }
    uint4 pk;
    pk.x = (unsigned)v[0] | ((unsigned)v[1] << 16);
    pk.y = (unsigned)v[2] | ((unsigned)v[3] << 16);
    pk.z = (unsigned)v[4] | ((unsigned)v[5] << 16);
    pk.w = (unsigned)v[6] | ((unsigned)v[7] << 16);
    ((uint4*)dst)[tid] = pk;
}

// ---- prep: Wout fragments for 16x16x32 (16-col tile, cols 5..15 zero) ----
__global__ void prep_wout(const float* __restrict__ Wout, unsigned short* __restrict__ dst) {
    int tid = blockIdx.x * 256 + threadIdx.x;   // 512 total
    if (tid >= 512) return;
    int l  = tid & 63;
    int kk = tid >> 6;
    int q  = l & 15;
    int kb = kk * 32 + (l >> 4) * 8;
    unsigned short v[8];
#pragma unroll
    for (int e = 0; e < 8; ++e) {
        float f = (q < 5) ? Wout[q * 256 + kb + e] : 0.0f;
        v[e] = f2bf(f);
    }
    uint4 pk;
    pk.x = (unsigned)v[0] | ((unsigned)v[1] << 16);
    pk.y = (unsigned)v[2] | ((unsigned)v[3] << 16);
    pk.z = (unsigned)v[4] | ((unsigned)v[5] << 16);
    pk.w = (unsigned)v[6] | ((unsigned)v[7] << 16);
    ((uint4*)dst)[tid] = pk;
}

__global__ void prep_bias(const float* __restrict__ bih, const float* __restrict__ bhh,
                          float* __restrict__ dst) {
    int tid = blockIdx.x * 256 + threadIdx.x;
    if (tid < 1024) dst[tid] = bih[tid] + bhh[tid];
}

// ---- main persistent-over-T kernel: 1 block = 64 samples, 16 waves, 4 waves/SIMD ----
// Double-buffered A tile -> ONE barrier per step; waves free-run across phases.
// LDS = 2*48KB (A2) + 64KB (c) = 160 KiB exactly.
__global__ __launch_bounds__(1024, 4)
void lstm_main(const float* __restrict__ x_in, const float* __restrict__ h_in,
               const float* __restrict__ c_in, const int* __restrict__ mask,
               const float* __restrict__ W_emb, const float* __restrict__ b_emb,
               const float* __restrict__ b_out,
               const unsigned short* __restrict__ wcat_fr,
               const unsigned short* __restrict__ wout_fr,
               const float* __restrict__ bias_g,
               float* __restrict__ out) {
    __shared__ unsigned short A2[2 * 64 * KDIM];  // 96 KB: double-buffered [h|e], SWZ
    __shared__ float c_lds[64 * RNN];             // 64 KB: fp32 c (wave-private cells)

    const int tid  = threadIdx.x;
    const int lane = tid & 63;
    const int w    = tid >> 6;         // wave 0..15 = unit-block
    const int base = blockIdx.x * 64;
    const int csub = lane & 15;
    const int kq   = lane >> 4;        // 0..3
    const int unit = w * 16 + csub;

    // ---- init: h0 -> A2 buf0 (bf16), c0 -> c_lds ----
#pragma unroll
    for (int m = 0; m < 4; ++m)
#pragma unroll
        for (int r = 0; r < 4; ++r) {
            int row = m * 16 + kq * 4 + r;
            float hv = h_in[(size_t)(base + row) * RNN + unit];
            c_lds[row * RNN + unit] = c_in[(size_t)(base + row) * RNN + unit];
            int byte = row * ROWB + unit * 2;
            byte ^= SWZ(row);
            *(unsigned short*)((char*)A2 + byte) = f2bf(hv);
        }
    // e(0) -> buf0 e-region
    {
        int row = tid >> 4;
        int jc  = (tid & 15) * 8;
        const float* xp = x_in + ((size_t)(base + row)) * 2;
        float x0 = xp[0], x1 = xp[1];
        unsigned pk[4];
#pragma unroll
        for (int e = 0; e < 8; e += 2) {
            int j = jc + e;
            float e0 = fmaxf(fmaf(x0, W_emb[j],     fmaf(x1, W_emb[128 + j],     b_emb[j])),     0.0f);
            float e1 = fmaxf(fmaf(x0, W_emb[j + 1], fmaf(x1, W_emb[128 + j + 1], b_emb[j + 1])), 0.0f);
            pk[e >> 1] = (unsigned)f2bf(e0) | ((unsigned)f2bf(e1) << 16);
        }
        int byte = row * ROWB + 512 + 2 * jc;
        byte ^= SWZ(row);
        *(uint4*)((char*)A2 + byte) = make_uint4(pk[0], pk[1], pk[2], pk[3]);
    }

    float bias4[4];
#pragma unroll
    for (int g = 0; g < 4; ++g) bias4[g] = bias_g[g * 256 + unit];
    const float bo = (csub < 5) ? b_out[csub] : 0.0f;

    const uint4* wfp = (const uint4*)wcat_fr + (size_t)w * (12 * 4 * 64) + lane;
    const uint4* wop = (const uint4*)wout_fr + lane;

    // persistent depth-2 weight pipeline (regs), wraps across steps
    bf16x8 bA[4], bB[4];
#pragma unroll
    for (int g = 0; g < 4; ++g) bA[g] = *(const bf16x8*)(wfp + (0 * 4 + g) * 64);
#pragma unroll
    for (int g = 0; g < 4; ++g) bB[g] = *(const bf16x8*)(wfp + (1 * 4 + g) * 64);

    BLOCK_SYNC();  // init state visible

    for (int t = 0; t < T_STEPS; ++t) {
        const int abC = (t & 1) * ABUF;         // buffer B(t) reads
        const int abN = ((t + 1) & 1) * ABUF;   // buffer C(t)/A(t+1) write

        // mask for step t: one coalesced load + ballot -> SGPR pair
        int mv = mask[(size_t)t * NBATCH + base + lane];
        unsigned long long mbits = __ballot(mv != 0);

        // ---- Phase B: gates 64 rows x 16 units x 4 gates (12 K=32 slices) ----
        f32x4 acc[4][4];
#pragma unroll
        for (int m = 0; m < 4; ++m)
#pragma unroll
            for (int g = 0; g < 4; ++g) {
                f32x4 z = {bias4[g], bias4[g], bias4[g], bias4[g]};
                acc[m][g] = z;
            }
#pragma unroll 1
        for (int kp = 0; kp < 6; ++kp) {
            int kk0 = kp * 2;
            {
#pragma unroll
                for (int m = 0; m < 4; ++m) {
                    int row = m * 16 + csub;
                    int byte = row * ROWB + kk0 * 64 + kq * 16;
                    byte ^= SWZ(row);
                    bf16x8 a = *(const bf16x8*)((const char*)A2 + abC + byte);
                    acc[m][0] = __builtin_amdgcn_mfma_f32_16x16x32_bf16(a, bA[0], acc[m][0], 0, 0, 0);
                    acc[m][1] = __builtin_amdgcn_mfma_f32_16x16x32_bf16(a, bA[1], acc[m][1], 0, 0, 0);
                    acc[m][2] = __builtin_amdgcn_mfma_f32_16x16x32_bf16(a, bA[2], acc[m][2], 0, 0, 0);
                    acc[m][3] = __builtin_amdgcn_mfma_f32_16x16x32_bf16(a, bA[3], acc[m][3], 0, 0, 0);
                }
                int kn = kk0 + 2; if (kn >= 12) kn -= 12;   // wraps to next step (same weights)
#pragma unroll
                for (int g = 0; g < 4; ++g)
                    bA[g] = *(const bf16x8*)(wfp + (kn * 4 + g) * 64);
            }
            {
                int kk1 = kk0 + 1;
#pragma unroll
                for (int m = 0; m < 4; ++m) {
                    int row = m * 16 + csub;
                    int byte = row * ROWB + kk1 * 64 + kq * 16;
                    byte ^= SWZ(row);
                    bf16x8 a = *(const bf16x8*)((const char*)A2 + abC + byte);
                    acc[m][0] = __builtin_amdgcn_mfma_f32_16x16x32_bf16(a, bB[0], acc[m][0], 0, 0, 0);
                    acc[m][1] = __builtin_amdgcn_mfma_f32_16x16x32_bf16(a, bB[1], acc[m][1], 0, 0, 0);
                    acc[m][2] = __builtin_amdgcn_mfma_f32_16x16x32_bf16(a, bB[2], acc[m][2], 0, 0, 0);
                    acc[m][3] = __builtin_amdgcn_mfma_f32_16x16x32_bf16(a, bB[3], acc[m][3], 0, 0, 0);
                }
                int kn = kk1 + 2; if (kn >= 12) kn -= 12;
#pragma unroll
                for (int g = 0; g < 4; ++g)
                    bB[g] = *(const bf16x8*)(wfp + (kn * 4 + g) * 64);
            }
        }

        // ---- Phase A(t+1): x-loads issued early (hide under Phase C) ----
        float ex0 = 0.0f, ex1 = 0.0f;
        int erow = tid >> 4, ejc = (tid & 15) * 8;
        if (t + 1 < T_STEPS) {
            const float* xp = x_in + ((size_t)(t + 1) * NBATCH + base + erow) * 2;
            ex0 = xp[0]; ex1 = xp[1];
        }

        // ---- Phase C: elementwise update; read h-old from buf C, write h-new to buf N ----
#pragma unroll
        for (int m = 0; m < 4; ++m)
#pragma unroll
            for (int r = 0; r < 4; ++r) {
                int row = m * 16 + kq * 4 + r;
                float cv = c_lds[row * RNN + unit];
                float iv = sigm_(acc[m][0][r]);
                float fv = sigm_(acc[m][1][r]);
                float gv = tanh_(acc[m][2][r]);
                float ov = sigm_(acc[m][3][r]);
                float cn = fmaf(fv, cv, iv * gv);
                float hn = ov * tanh_(cn);
                int msk = (int)((mbits >> row) & 1ull);
                int hb = row * ROWB + unit * 2;
                hb ^= SWZ(row);
                unsigned short hold = *(const unsigned short*)((const char*)A2 + abC + hb);
                unsigned short hnew = msk ? f2bf(hn) : hold;
                *(unsigned short*)((char*)A2 + abN + hb) = hnew;
                if (msk) c_lds[row * RNN + unit] = cn;
            }

        if (t + 1 < T_STEPS) {
            unsigned pk[4];
#pragma unroll
            for (int e = 0; e < 8; e += 2) {
                int j = ejc + e;
                float e0 = fmaxf(fmaf(ex0, W_emb[j],     fmaf(ex1, W_emb[128 + j],     b_emb[j])),     0.0f);
                float e1 = fmaxf(fmaf(ex0, W_emb[j + 1], fmaf(ex1, W_emb[128 + j + 1], b_emb[j + 1])), 0.0f);
                pk[e >> 1] = (unsigned)f2bf(e0) | ((unsigned)f2bf(e1) << 16);
            }
            int byte = erow * ROWB + 512 + 2 * ejc;
            byte ^= SWZ(erow);
            *(uint4*)((char*)A2 + abN + byte) = make_uint4(pk[0], pk[1], pk[2], pk[3]);
        }

        BLOCK_SYNC();  // the ONE barrier: h(t+1)/e(t+1) visible to everyone

        // ---- Phase D(t): out = h_new @ Wout^T + b_out (waves 0..3), overlaps B(t+1) ----
        if (w < 4) {
            f32x4 oacc = {bo, bo, bo, bo};
#pragma unroll
            for (int kk = 0; kk < 8; ++kk) {
                int row = w * 16 + csub;
                int byte = row * ROWB + kk * 64 + kq * 16;
                byte ^= SWZ(row);
                bf16x8 a  = *(const bf16x8*)((const char*)A2 + abN + byte);
                bf16x8 bw = *(const bf16x8*)(wop + kk * 64);
                oacc = __builtin_amdgcn_mfma_f32_16x16x32_bf16(a, bw, oacc, 0, 0, 0);
            }
            if (csub < 5) {
#pragma unroll
                for (int r = 0; r < 4; ++r) {
                    int row = w * 16 + kq * 4 + r;
                    int msk = (int)((mbits >> row) & 1ull);
                    out[((size_t)t * NBATCH + base + row) * 5 + csub] = msk ? oacc[r] : 0.0f;
                }
            }
        }
        // no extra barrier: D reads buf N h-region (also read by B(t+1)); C(t+1)
        // writes buf C — disjoint. c_lds cells are wave-private.
    }

    // ---- final states: h from A2 buf (T&1), c from c_lds ----
    const int abF = (T_STEPS & 1) * ABUF;
    float* hout = out + (size_t)T_STEPS * NBATCH * 5;
    float* cout = hout + (size_t)NBATCH * RNN;
#pragma unroll
    for (int m = 0; m < 4; ++m)
#pragma unroll
        for (int r = 0; r < 4; ++r) {
            int row = m * 16 + kq * 4 + r;
            int byte = row * ROWB + unit * 2;
            byte ^= SWZ(row);
            hout[(size_t)(base + row) * RNN + unit] =
                bf2f(*(const unsigned short*)((const char*)A2 + abF + byte));
            cout[(size_t)(base + row) * RNN + unit] = c_lds[row * RNN + unit];
        }
}

extern "C" void kernel_launch(void* const* d_in, const int* in_sizes, int n_in,
                              void* d_out, int out_size, void* d_ws, size_t ws_size,
                              hipStream_t stream) {
    (void)in_sizes; (void)n_in; (void)out_size; (void)ws_size;
    const float* x_in = (const float*)d_in[0];
    const float* h0   = (const float*)d_in[1];
    const float* c0   = (const float*)d_in[2];
    const int*   mk   = (const int*)d_in[3];
    const float* Wemb = (const float*)d_in[4];
    const float* bemb = (const float*)d_in[5];
    const float* Wih  = (const float*)d_in[6];
    const float* bih  = (const float*)d_in[7];
    const float* Whh  = (const float*)d_in[8];
    const float* bhh  = (const float*)d_in[9];
    const float* Wout = (const float*)d_in[10];
    const float* bout = (const float*)d_in[11];

    unsigned short* wcat = (unsigned short*)d_ws;        // 49152 uint4 = 768 KB
    unsigned short* wouf = wcat + 393216;                // 512 uint4 = 8 KB
    float*          bsg  = (float*)(wouf + 4096);        // 1024 f32

    prep_wcat<<<192, 256, 0, stream>>>(Whh, Wih, wcat);
    prep_wout<<<2, 256, 0, stream>>>(Wout, wouf);
    prep_bias<<<4, 256, 0, stream>>>(bih, bhh, bsg);

    float* outp = (float*)d_out;
    lstm_main<<<1024, 1024, 0, stream>>>(x_in, h0, c0, mk, Wemb, bemb, bout,
                                         wcat, wouf, bsg, outp);
}

// Round 10
// 2494.291 us; speedup vs baseline: 1.0127x; 1.0127x over previous
//
#include <hip/hip_runtime.h>

#define T_STEPS 19
#define NBATCH  65536
#define RNN     256
#define EMB     128
#define KDIM    384   // RNN + EMB
#define ROWB    768   // KDIM * 2 bytes (LDS row stride)
#define SWZ(row) (((row) & 15) << 4)

typedef __bf16 bf16x8 __attribute__((ext_vector_type(8)));
typedef float  f32x4  __attribute__((ext_vector_type(4)));

#define BLOCK_SYNC() asm volatile("s_waitcnt lgkmcnt(0)\n\ts_barrier" ::: "memory")

__device__ __forceinline__ unsigned short f2bf(float f) {
    unsigned u = __float_as_uint(f);
    u += 0x7fffu + ((u >> 16) & 1u);
    return (unsigned short)(u >> 16);
}
__device__ __forceinline__ float bf2f(unsigned short u) {
    return __uint_as_float(((unsigned)u) << 16);
}
__device__ __forceinline__ float sigm_(float x) {
    float e = __expf(-x);
    return __builtin_amdgcn_rcpf(1.0f + e);
}
__device__ __forceinline__ float tanh_(float x) {
    float e = __expf(2.0f * x);
    return 1.0f - 2.0f * __builtin_amdgcn_rcpf(e + 1.0f);
}

// ---- prep: Wcat fragments, unit-block-major so 4 row-block waves share bytes ----
// uint4 idx = ((ub*12 + kk)*16 + g*4 + usub)*64 + l
//   j = g*256 + ub*64 + usub*16 + (l&15) ; k = kk*32 + (l>>4)*8 + e
__global__ void prep_wcat(const float* __restrict__ Whh, const float* __restrict__ Wih,
                          unsigned short* __restrict__ dst) {
    int tid = blockIdx.x * 256 + threadIdx.x;   // 49152 total
    int l    = tid & 63;
    int p    = tid >> 6;         // 0..767
    int usub = p & 3;
    int g    = (p >> 2) & 3;
    int kk   = (p >> 4) % 12;
    int ub   = (p >> 4) / 12;    // 0..3
    int j    = g * 256 + ub * 64 + usub * 16 + (l & 15);
    int kb   = kk * 32 + (l >> 4) * 8;
    unsigned short v[8];
#pragma unroll
    for (int e = 0; e < 8; ++e) {
        int k = kb + e;
        float f = (k < 256) ? Whh[j * 256 + k] : Wih[j * 128 + (k - 256)];
        v[e] = f2bf(f);
    }
    uint4 pk;
    pk.x = (unsigned)v[0] | ((unsigned)v[1] << 16);
    pk.y = (unsigned)v[2] | ((unsigned)v[3] << 16);
    pk.z = (unsigned)v[4] | ((unsigned)v[5] << 16);
    pk.w = (unsigned)v[6] | ((unsigned)v[7] << 16);
    ((uint4*)dst)[tid] = pk;
}

// ---- prep: Wout fragments for 16x16x32 (16-col tile, cols 5..15 zero) ----
__global__ void prep_wout(const float* __restrict__ Wout, unsigned short* __restrict__ dst) {
    int tid = blockIdx.x * 256 + threadIdx.x;   // 512 total
    if (tid >= 512) return;
    int l  = tid & 63;
    int kk = tid >> 6;
    int q  = l & 15;
    int kb = kk * 32 + (l >> 4) * 8;
    unsigned short v[8];
#pragma unroll
    for (int e = 0; e < 8; ++e) {
        float f = (q < 5) ? Wout[q * 256 + kb + e] : 0.0f;
        v[e] = f2bf(f);
    }
    uint4 pk;
    pk.x = (unsigned)v[0] | ((unsigned)v[1] << 16);
    pk.y = (unsigned)v[2] | ((unsigned)v[3] << 16);
    pk.z = (unsigned)v[4] | ((unsigned)v[5] << 16);
    pk.w = (unsigned)v[6] | ((unsigned)v[7] << 16);
    ((uint4*)dst)[tid] = pk;
}

__global__ void prep_bias(const float* __restrict__ bih, const float* __restrict__ bhh,
                          float* __restrict__ dst) {
    int tid = blockIdx.x * 256 + threadIdx.x;
    if (tid < 1024) dst[tid] = bih[tid] + bhh[tid];
}

// ---- main persistent-over-T kernel: 1 block = 64 samples, 16 waves, 4 waves/SIMD ----
// Wave (ub, rb): unit-block ub (64 units x 4 gates), row-block rb (16 rows).
// 4 rb-waves per ub read IDENTICAL weight fragments in lockstep -> L1 serves 3/4.
// acc = 16 f32x4 (64 AGPR); c wave-private (16 VGPR); one A-frag read per kk.
__global__ __launch_bounds__(1024, 4)
void lstm_main(const float* __restrict__ x_in, const float* __restrict__ h_in,
               const float* __restrict__ c_in, const int* __restrict__ mask,
               const float* __restrict__ W_emb, const float* __restrict__ b_emb,
               const float* __restrict__ b_out,
               const unsigned short* __restrict__ wcat_fr,
               const unsigned short* __restrict__ wout_fr,
               const float* __restrict__ bias_g,
               float* __restrict__ out) {
    __shared__ unsigned short A_lds[64 * KDIM];   // 48 KB, XOR-swizzled
    __shared__ float b_lds[1024];                 // 4 KB: bias per gate-col
    __shared__ float we_lds[384];                 // W_emb(256) + b_emb(128)
    __shared__ int   m_lds[2][64];

    const int tid  = threadIdx.x;
    const int lane = tid & 63;
    const int w    = tid >> 6;         // wave 0..15
    const int ub   = w & 3;            // unit-block (64 units)
    const int rb   = w >> 2;           // row-block (16 rows)
    const int base = blockIdx.x * 64;
    const int csub = lane & 15;
    const int kq   = lane >> 4;        // 0..3

    float c_reg[4][4];                 // [usub][r] fp32 c for this lane's 16 cells

    // ---- init: h0 -> A_lds (bf16), c0 -> regs; bias/W_emb -> LDS ----
#pragma unroll
    for (int usub = 0; usub < 4; ++usub)
#pragma unroll
        for (int r = 0; r < 4; ++r) {
            int row  = rb * 16 + kq * 4 + r;
            int unit = ub * 64 + usub * 16 + csub;
            float hv = h_in[(size_t)(base + row) * RNN + unit];
            c_reg[usub][r] = c_in[(size_t)(base + row) * RNN + unit];
            int byte = row * ROWB + unit * 2;
            byte ^= SWZ(row);
            A_lds[byte >> 1] = f2bf(hv);
        }
    if (tid < 384) we_lds[tid] = (tid < 256) ? W_emb[tid] : b_emb[tid - 256];
    if (tid < 1024 && tid >= 0) b_lds[tid] = bias_g[tid];
    const float bo = (csub < 5) ? b_out[csub] : 0.0f;

    const uint4* wfp = (const uint4*)wcat_fr + (size_t)ub * (12 * 16 * 64) + lane;
    const uint4* wop = (const uint4*)wout_fr + lane;

    BLOCK_SYNC();  // init LDS visible

    for (int t = 0; t < T_STEPS; ++t) {
        // ---- Phase A: e = relu(x @ W_emb + b_emb) -> A_lds k=256..383; mask -> LDS ----
        {
            int row = tid >> 4;
            int jc  = (tid & 15) * 8;
            const float* xp = x_in + ((size_t)t * NBATCH + base + row) * 2;
            float x0 = xp[0], x1 = xp[1];
            unsigned pk[4];
#pragma unroll
            for (int e = 0; e < 8; e += 2) {
                int j = jc + e;
                float e0 = fmaxf(fmaf(x0, we_lds[j],     fmaf(x1, we_lds[128 + j],     we_lds[256 + j])),     0.0f);
                float e1 = fmaxf(fmaf(x0, we_lds[j + 1], fmaf(x1, we_lds[128 + j + 1], we_lds[256 + j + 1])), 0.0f);
                pk[e >> 1] = (unsigned)f2bf(e0) | ((unsigned)f2bf(e1) << 16);
            }
            int byte = row * ROWB + 512 + 2 * jc;
            byte ^= SWZ(row);
            *(uint4*)((char*)A_lds + byte) = make_uint4(pk[0], pk[1], pk[2], pk[3]);
            if (tid < 64) m_lds[t & 1][tid] = mask[(size_t)t * NBATCH + base + tid];
        }
        BLOCK_SYNC();  // bar1: A_lds + mask ready

        // ---- Phase B: gates 16 rows x (64 units x 4 gates), 12 K=32 slices ----
        f32x4 acc[4][4];   // [g][usub]
#pragma unroll
        for (int g = 0; g < 4; ++g)
#pragma unroll
            for (int usub = 0; usub < 4; ++usub) {
                float b = b_lds[g * 256 + ub * 64 + usub * 16 + csub];
                f32x4 z = {b, b, b, b};
                acc[g][usub] = z;
            }
#pragma unroll 2
        for (int kk = 0; kk < 12; ++kk) {
            int row = rb * 16 + csub;
            int byte = row * ROWB + kk * 64 + kq * 16;
            byte ^= SWZ(row);
            bf16x8 a = *(const bf16x8*)((const char*)A_lds + byte);
            const uint4* wk = wfp + (size_t)kk * (16 * 64);
#pragma unroll
            for (int f = 0; f < 16; ++f) {
                bf16x8 bfr = *(const bf16x8*)(wk + f * 64);
                acc[f >> 2][f & 3] =
                    __builtin_amdgcn_mfma_f32_16x16x32_bf16(a, bfr, acc[f >> 2][f & 3], 0, 0, 0);
            }
        }
        BLOCK_SYNC();  // bar2: all A_lds reads done before h overwrite

        // ---- Phase C: elementwise update; c in regs, h (bf16) back to A_lds ----
#pragma unroll
        for (int usub = 0; usub < 4; ++usub)
#pragma unroll
            for (int r = 0; r < 4; ++r) {
                int row  = rb * 16 + kq * 4 + r;
                int unit = ub * 64 + usub * 16 + csub;
                float iv = sigm_(acc[0][usub][r]);
                float fv = sigm_(acc[1][usub][r]);
                float gv = tanh_(acc[2][usub][r]);
                float ov = sigm_(acc[3][usub][r]);
                float cn = fmaf(fv, c_reg[usub][r], iv * gv);
                float hn = ov * tanh_(cn);
                if (m_lds[t & 1][row]) {
                    c_reg[usub][r] = cn;
                    int byte = row * ROWB + unit * 2;
                    byte ^= SWZ(row);
                    A_lds[byte >> 1] = f2bf(hn);
                }
            }
        BLOCK_SYNC();  // bar3: new h visible

        // ---- Phase D: out = h @ Wout^T + b_out (waves 0..3 = rb 0, ub as row-block) ----
        if (w < 4) {
            f32x4 oacc = {bo, bo, bo, bo};
#pragma unroll
            for (int kk = 0; kk < 8; ++kk) {
                int row = w * 16 + csub;
                int byte = row * ROWB + kk * 64 + kq * 16;
                byte ^= SWZ(row);
                bf16x8 a  = *(const bf16x8*)((const char*)A_lds + byte);
                bf16x8 bw = *(const bf16x8*)(wop + kk * 64);
                oacc = __builtin_amdgcn_mfma_f32_16x16x32_bf16(a, bw, oacc, 0, 0, 0);
            }
            if (csub < 5) {
#pragma unroll
                for (int r = 0; r < 4; ++r) {
                    int row = w * 16 + kq * 4 + r;
                    int m = m_lds[t & 1][row];
                    out[((size_t)t * NBATCH + base + row) * 5 + csub] = m ? oacc[r] : 0.0f;
                }
            }
        }
        // no barrier: D reads h-region (k<256) + m_lds[t&1]; next A writes e-region
        // (k>=256) + m_lds[(t+1)&1] — disjoint. C(t+1) writes are behind bar1+bar2.
    }

    // ---- final states: h from A_lds (bf16), c from regs (fp32) ----
    float* hout = out + (size_t)T_STEPS * NBATCH * 5;
    float* cout = hout + (size_t)NBATCH * RNN;
#pragma unroll
    for (int usub = 0; usub < 4; ++usub)
#pragma unroll
        for (int r = 0; r < 4; ++r) {
            int row  = rb * 16 + kq * 4 + r;
            int unit = ub * 64 + usub * 16 + csub;
            int byte = row * ROWB + unit * 2;
            byte ^= SWZ(row);
            hout[(size_t)(base + row) * RNN + unit] = bf2f(A_lds[byte >> 1]);
            cout[(size_t)(base + row) * RNN + unit] = c_reg[usub][r];
        }
}

extern "C" void kernel_launch(void* const* d_in, const int* in_sizes, int n_in,
                              void* d_out, int out_size, void* d_ws, size_t ws_size,
                              hipStream_t stream) {
    (void)in_sizes; (void)n_in; (void)out_size; (void)ws_size;
    const float* x_in = (const float*)d_in[0];
    const float* h0   = (const float*)d_in[1];
    const float* c0   = (const float*)d_in[2];
    const int*   mk   = (const int*)d_in[3];
    const float* Wemb = (const float*)d_in[4];
    const float* bemb = (const float*)d_in[5];
    const float* Wih  = (const float*)d_in[6];
    const float* bih  = (const float*)d_in[7];
    const float* Whh  = (const float*)d_in[8];
    const float* bhh  = (const float*)d_in[9];
    const float* Wout = (const float*)d_in[10];
    const float* bout = (const float*)d_in[11];

    unsigned short* wcat = (unsigned short*)d_ws;        // 49152 uint4 = 768 KB
    unsigned short* wouf = wcat + 393216;                // 512 uint4 = 8 KB
    float*          bsg  = (float*)(wouf + 4096);        // 1024 f32

    prep_wcat<<<192, 256, 0, stream>>>(Whh, Wih, wcat);
    prep_wout<<<2, 256, 0, stream>>>(Wout, wouf);
    prep_bias<<<4, 256, 0, stream>>>(bih, bhh, bsg);

    float* outp = (float*)d_out;
    lstm_main<<<1024, 1024, 0, stream>>>(x_in, h0, c0, mk, Wemb, bemb, bout,
                                         wcat, wouf, bsg, outp);
}

// Round 11
// 2265.102 us; speedup vs baseline: 1.1151x; 1.1012x over previous
//
#include <hip/hip_runtime.h>

#define T_STEPS 19
#define NBATCH  65536
#define RNN     256
#define EMB     128
#define KDIM    384   // RNN + EMB
#define ROWB    768   // KDIM * 2 bytes (LDS row stride)
#define SWZ(row) (((row) & 15) << 4)

typedef __bf16 bf16x8 __attribute__((ext_vector_type(8)));
typedef float  f32x4  __attribute__((ext_vector_type(4)));

#define BLOCK_SYNC() asm volatile("s_waitcnt lgkmcnt(0)\n\ts_barrier" ::: "memory")

__device__ __forceinline__ unsigned short f2bf(float f) {
    unsigned u = __float_as_uint(f);
    u += 0x7fffu + ((u >> 16) & 1u);
    return (unsigned short)(u >> 16);
}
__device__ __forceinline__ float bf2f(unsigned short u) {
    return __uint_as_float(((unsigned)u) << 16);
}
__device__ __forceinline__ float sigm_(float x) {
    float e = __expf(-x);
    return __builtin_amdgcn_rcpf(1.0f + e);
}
__device__ __forceinline__ float tanh_(float x) {
    float e = __expf(2.0f * x);
    return 1.0f - 2.0f * __builtin_amdgcn_rcpf(e + 1.0f);
}

// ---- prep: Wcat fragments for 16x16x32 MFMA, wave-private slices (round-7 layout) ----
// uint4 idx = ((w*12 + kk)*4 + g)*64 + l
//   j = g*256 + w*16 + (l&15) ; k = kk*32 + (l>>4)*8 + e
__global__ void prep_wcat(const float* __restrict__ Whh, const float* __restrict__ Wih,
                          unsigned short* __restrict__ dst) {
    int tid = blockIdx.x * 256 + threadIdx.x;   // 49152 total
    int l   = tid & 63;
    int p   = tid >> 6;
    int g   = p & 3;
    int kkw = p >> 2;
    int kk  = kkw % 12;
    int w   = kkw / 12;
    int j   = g * 256 + w * 16 + (l & 15);
    int kb  = kk * 32 + (l >> 4) * 8;
    unsigned short v[8];
#pragma unroll
    for (int e = 0; e < 8; ++e) {
        int k = kb + e;
        float f = (k < 256) ? Whh[j * 256 + k] : Wih[j * 128 + (k - 256)];
        v[e] = f2bf(f);
    }
    uint4 pk;
    pk.x = (unsigned)v[0] | ((unsigned)v[1] << 16);
    pk.y = (unsigned)v[2] | ((unsigned)v[3] << 16);
    pk.z = (unsigned)v[4] | ((unsigned)v[5] << 16);
    pk.w = (unsigned)v[6] | ((unsigned)v[7] << 16);
    ((uint4*)dst)[tid] = pk;
}

// ---- prep: Wout fragments for 16x16x32 (16-col tile, cols 5..15 zero) ----
__global__ void prep_wout(const float* __restrict__ Wout, unsigned short* __restrict__ dst) {
    int tid = blockIdx.x * 256 + threadIdx.x;   // 512 total
    if (tid >= 512) return;
    int l  = tid & 63;
    int kk = tid >> 6;
    int q  = l & 15;
    int kb = kk * 32 + (l >> 4) * 8;
    unsigned short v[8];
#pragma unroll
    for (int e = 0; e < 8; ++e) {
        float f = (q < 5) ? Wout[q * 256 + kb + e] : 0.0f;
        v[e] = f2bf(f);
    }
    uint4 pk;
    pk.x = (unsigned)v[0] | ((unsigned)v[1] << 16);
    pk.y = (unsigned)v[2] | ((unsigned)v[3] << 16);
    pk.z = (unsigned)v[4] | ((unsigned)v[5] << 16);
    pk.w = (unsigned)v[6] | ((unsigned)v[7] << 16);
    ((uint4*)dst)[tid] = pk;
}

__global__ void prep_bias(const float* __restrict__ bih, const float* __restrict__ bhh,
                          float* __restrict__ dst) {
    int tid = blockIdx.x * 256 + threadIdx.x;
    if (tid < 1024) dst[tid] = bih[tid] + bhh[tid];
}

// ---- main persistent-over-T kernel: 1 block = 64 samples, 16 waves, 4 waves/SIMD ----
// Round-7 structure + staggered kk start (decorrelate same-SIMD waitcnt stalls)
// + ballot mask + we_lds.
__global__ __launch_bounds__(1024, 4)
void lstm_main(const float* __restrict__ x_in, const float* __restrict__ h_in,
               const float* __restrict__ c_in, const int* __restrict__ mask,
               const float* __restrict__ W_emb, const float* __restrict__ b_emb,
               const float* __restrict__ b_out,
               const unsigned short* __restrict__ wcat_fr,
               const unsigned short* __restrict__ wout_fr,
               const float* __restrict__ bias_g,
               float* __restrict__ out) {
    __shared__ unsigned short A_lds[64 * KDIM];   // 48 KB, XOR-swizzled
    __shared__ float c_lds[64 * RNN];             // 64 KB fp32 c state
    __shared__ float we_lds[384];                 // W_emb(256) + b_emb(128)

    const int tid  = threadIdx.x;
    const int lane = tid & 63;
    const int w    = tid >> 6;         // wave 0..15 = unit-block
    const int base = blockIdx.x * 64;
    const int csub = lane & 15;
    const int kq   = lane >> 4;        // 0..3
    const int unit = w * 16 + csub;

    // stagger: SIMD-mates start their kk sweep at offsets 0,3,6,9 (covers both
    // w%4 and w>>2 wave->SIMD assignment conventions)
    const int kks = (((w & 3) + (w >> 2)) & 3) * 3;

    // init: h0 -> A_lds (bf16), c0 -> c_lds (fp32)
#pragma unroll
    for (int m = 0; m < 4; ++m)
#pragma unroll
        for (int r = 0; r < 4; ++r) {
            int row = m * 16 + kq * 4 + r;
            float hv = h_in[(size_t)(base + row) * RNN + unit];
            c_lds[row * RNN + unit] = c_in[(size_t)(base + row) * RNN + unit];
            int byte = row * ROWB + unit * 2;
            byte ^= SWZ(row);
            A_lds[byte >> 1] = f2bf(hv);
        }
    if (tid < 384) we_lds[tid] = (tid < 256) ? W_emb[tid] : b_emb[tid - 256];

    float bias4[4];
#pragma unroll
    for (int g = 0; g < 4; ++g) bias4[g] = bias_g[g * 256 + unit];
    const float bo = (csub < 5) ? b_out[csub] : 0.0f;

    const uint4* wfp = (const uint4*)wcat_fr + (size_t)w * (12 * 4 * 64) + lane;
    const uint4* wop = (const uint4*)wout_fr + lane;

    // persistent depth-2 weight pipeline (regs), staggered start, wraps across steps
    int kpre = kks + 1; if (kpre >= 12) kpre -= 12;
    bf16x8 bA[4], bB[4];
#pragma unroll
    for (int g = 0; g < 4; ++g) bA[g] = *(const bf16x8*)(wfp + (kks  * 4 + g) * 64);
#pragma unroll
    for (int g = 0; g < 4; ++g) bB[g] = *(const bf16x8*)(wfp + (kpre * 4 + g) * 64);

    BLOCK_SYNC();  // init LDS (h, c, we_lds) visible

    for (int t = 0; t < T_STEPS; ++t) {
        // mask for step t: per-wave coalesced load + ballot (no LDS, no straggler wave)
        int mv = mask[(size_t)t * NBATCH + base + lane];
        unsigned long long mbits = __ballot(mv != 0);

        // ---- Phase A: e = relu(x @ W_emb + b_emb) -> A_lds k=256..383 ----
        {
            int row = tid >> 4;
            int jc  = (tid & 15) * 8;
            const float* xp = x_in + ((size_t)t * NBATCH + base + row) * 2;
            float x0 = xp[0], x1 = xp[1];
            unsigned pk[4];
#pragma unroll
            for (int e = 0; e < 8; e += 2) {
                int j = jc + e;
                float e0 = fmaxf(fmaf(x0, we_lds[j],     fmaf(x1, we_lds[128 + j],     we_lds[256 + j])),     0.0f);
                float e1 = fmaxf(fmaf(x0, we_lds[j + 1], fmaf(x1, we_lds[128 + j + 1], we_lds[256 + j + 1])), 0.0f);
                pk[e >> 1] = (unsigned)f2bf(e0) | ((unsigned)f2bf(e1) << 16);
            }
            int byte = row * ROWB + 512 + 2 * jc;
            byte ^= SWZ(row);
            *(uint4*)((char*)A_lds + byte) = make_uint4(pk[0], pk[1], pk[2], pk[3]);
        }
        BLOCK_SYNC();  // bar1: A_lds ready

        // ---- Phase B: gates 64 rows x 16 units x 4 gates, staggered 12 K=32 slices ----
        f32x4 acc[4][4];
#pragma unroll
        for (int m = 0; m < 4; ++m)
#pragma unroll
            for (int g = 0; g < 4; ++g) {
                f32x4 z = {bias4[g], bias4[g], bias4[g], bias4[g]};
                acc[m][g] = z;
            }
        int ka = kks;
        int kb = kpre;
#pragma unroll 1
        for (int kp = 0; kp < 6; ++kp) {
            {
#pragma unroll
                for (int m = 0; m < 4; ++m) {
                    int row = m * 16 + csub;
                    int byte = row * ROWB + ka * 64 + kq * 16;
                    byte ^= SWZ(row);
                    bf16x8 a = *(const bf16x8*)((const char*)A_lds + byte);
                    acc[m][0] = __builtin_amdgcn_mfma_f32_16x16x32_bf16(a, bA[0], acc[m][0], 0, 0, 0);
                    acc[m][1] = __builtin_amdgcn_mfma_f32_16x16x32_bf16(a, bA[1], acc[m][1], 0, 0, 0);
                    acc[m][2] = __builtin_amdgcn_mfma_f32_16x16x32_bf16(a, bA[2], acc[m][2], 0, 0, 0);
                    acc[m][3] = __builtin_amdgcn_mfma_f32_16x16x32_bf16(a, bA[3], acc[m][3], 0, 0, 0);
                }
                int kn = ka + 2; if (kn >= 12) kn -= 12;   // wraps to next step (same weights)
#pragma unroll
                for (int g = 0; g < 4; ++g)
                    bA[g] = *(const bf16x8*)(wfp + (kn * 4 + g) * 64);
                ka = kn;
            }
            {
#pragma unroll
                for (int m = 0; m < 4; ++m) {
                    int row = m * 16 + csub;
                    int byte = row * ROWB + kb * 64 + kq * 16;
                    byte ^= SWZ(row);
                    bf16x8 a = *(const bf16x8*)((const char*)A_lds + byte);
                    acc[m][0] = __builtin_amdgcn_mfma_f32_16x16x32_bf16(a, bB[0], acc[m][0], 0, 0, 0);
                    acc[m][1] = __builtin_amdgcn_mfma_f32_16x16x32_bf16(a, bB[1], acc[m][1], 0, 0, 0);
                    acc[m][2] = __builtin_amdgcn_mfma_f32_16x16x32_bf16(a, bB[2], acc[m][2], 0, 0, 0);
                    acc[m][3] = __builtin_amdgcn_mfma_f32_16x16x32_bf16(a, bB[3], acc[m][3], 0, 0, 0);
                }
                int kn = kb + 2; if (kn >= 12) kn -= 12;
#pragma unroll
                for (int g = 0; g < 4; ++g)
                    bB[g] = *(const bf16x8*)(wfp + (kn * 4 + g) * 64);
                kb = kn;
            }
        }
        BLOCK_SYNC();  // bar2: all A_lds reads done before h overwrite

        // ---- Phase C: elementwise update; c in LDS, h (bf16) back to A_lds ----
#pragma unroll
        for (int m = 0; m < 4; ++m)
#pragma unroll
            for (int r = 0; r < 4; ++r) {
                int row = m * 16 + kq * 4 + r;
                float cv = c_lds[row * RNN + unit];
                float iv = sigm_(acc[m][0][r]);
                float fv = sigm_(acc[m][1][r]);
                float gv = tanh_(acc[m][2][r]);
                float ov = sigm_(acc[m][3][r]);
                float cn = fmaf(fv, cv, iv * gv);
                float hn = ov * tanh_(cn);
                int msk = (int)((mbits >> row) & 1ull);
                if (msk) {
                    c_lds[row * RNN + unit] = cn;
                    int byte = row * ROWB + unit * 2;
                    byte ^= SWZ(row);
                    A_lds[byte >> 1] = f2bf(hn);
                }
            }
        BLOCK_SYNC();  // bar3: new h visible

        // ---- Phase D: out = h @ Wout^T + b_out (waves 0..3), overlaps next Phase A ----
        if (w < 4) {
            f32x4 oacc = {bo, bo, bo, bo};
#pragma unroll
            for (int kk = 0; kk < 8; ++kk) {
                int row = w * 16 + csub;
                int byte = row * ROWB + kk * 64 + kq * 16;
                byte ^= SWZ(row);
                bf16x8 a  = *(const bf16x8*)((const char*)A_lds + byte);
                bf16x8 bw = *(const bf16x8*)(wop + kk * 64);
                oacc = __builtin_amdgcn_mfma_f32_16x16x32_bf16(a, bw, oacc, 0, 0, 0);
            }
            if (csub < 5) {
#pragma unroll
                for (int r = 0; r < 4; ++r) {
                    int row = w * 16 + kq * 4 + r;
                    int msk = (int)((mbits >> row) & 1ull);
                    out[((size_t)t * NBATCH + base + row) * 5 + csub] = msk ? oacc[r] : 0.0f;
                }
            }
        }
        // no barrier: D reads h-region (k<256); next A writes e-region (k>=256) — disjoint.
        // C(t+1) writes are behind bar1+bar2.
    }

    // ---- final states: h from A_lds (bf16), c from c_lds (fp32) ----
    float* hout = out + (size_t)T_STEPS * NBATCH * 5;
    float* cout = hout + (size_t)NBATCH * RNN;
#pragma unroll
    for (int m = 0; m < 4; ++m)
#pragma unroll
        for (int r = 0; r < 4; ++r) {
            int row = m * 16 + kq * 4 + r;
            int byte = row * ROWB + unit * 2;
            byte ^= SWZ(row);
            hout[(size_t)(base + row) * RNN + unit] = bf2f(A_lds[byte >> 1]);
            cout[(size_t)(base + row) * RNN + unit] = c_lds[row * RNN + unit];
        }
}

extern "C" void kernel_launch(void* const* d_in, const int* in_sizes, int n_in,
                              void* d_out, int out_size, void* d_ws, size_t ws_size,
                              hipStream_t stream) {
    (void)in_sizes; (void)n_in; (void)out_size; (void)ws_size;
    const float* x_in = (const float*)d_in[0];
    const float* h0   = (const float*)d_in[1];
    const float* c0   = (const float*)d_in[2];
    const int*   mk   = (const int*)d_in[3];
    const float* Wemb = (const float*)d_in[4];
    const float* bemb = (const float*)d_in[5];
    const float* Wih  = (const float*)d_in[6];
    const float* bih  = (const float*)d_in[7];
    const float* Whh  = (const float*)d_in[8];
    const float* bhh  = (const float*)d_in[9];
    const float* Wout = (const float*)d_in[10];
    const float* bout = (const float*)d_in[11];

    unsigned short* wcat = (unsigned short*)d_ws;        // 49152 uint4 = 768 KB
    unsigned short* wouf = wcat + 393216;                // 512 uint4 = 8 KB
    float*          bsg  = (float*)(wouf + 4096);        // 1024 f32

    prep_wcat<<<192, 256, 0, stream>>>(Whh, Wih, wcat);
    prep_wout<<<2, 256, 0, stream>>>(Wout, wouf);
    prep_bias<<<4, 256, 0, stream>>>(bih, bhh, bsg);

    float* outp = (float*)d_out;
    lstm_main<<<1024, 1024, 0, stream>>>(x_in, h0, c0, mk, Wemb, bemb, bout,
                                         wcat, wouf, bsg, outp);
}